// Round 5
// baseline (225.631 us; speedup 1.0000x reference)
//
#include <hip/hip_runtime.h>
#include <math.h>

// Cost weights / focal params (match reference)
#define W_CLASS 1.0f
#define W_BBOX  5.0f
#define W_GIOU  2.0f
#define F_ALPHA 0.25f
#define F_EPS   1e-8f

typedef float f2 __attribute__((ext_vector_type(2)));

#define ROWS 10              // pred rows per block (14400 = 1440 * 10)
#define TPB  320             // 5 waves
#define TCHUNK (TPB * 2)     // 640 targets per chunk
// T = 3200 -> 5 chunks, exact

// v_rcp_f32 + one Newton step (bit-identical softmax denominator vs passing runs)
__device__ __forceinline__ float fast_rcp_nr(float x) {
    float r = __builtin_amdgcn_rcpf(x);
    r = fmaf(fmaf(-x, r, 1.0f), r, r);
    return r;
}

// One block owns ROWS pred rows.
//  Phase A (once per row, no grid redundancy): focal class-cost table -> LDS.
//  Phase B: loop over 5 target chunks; 2 targets/thread; 10-row inner unroll;
//           f2 nontemporal stores.
__global__ __launch_bounds__(TPB)
void fused_cost_kernel(const float* __restrict__ logits,       // [N,128]
                       const float4* __restrict__ pred_boxes,  // [N,4] cxcywh
                       const float4* __restrict__ tgt_bbox,    // [T,4] cxcywh
                       const int* __restrict__ tgt_ids,        // [T]
                       float* __restrict__ out,                // [N,T]
                       int T) {
    __shared__ float delta[ROWS * 128];   // 5 KB

    const int n0 = blockIdx.x * ROWS;

    // ---------------- Phase A: class-cost table -> LDS (once) ----------------
    {
        const int wave = threadIdx.x >> 6;
        const int lane = threadIdx.x & 63;
        #pragma unroll
        for (int rr = 0; rr < 2; ++rr) {
            const int lr = wave * 2 + rr;            // 0..9
            const int n = n0 + lr;
            f2 x = ((const f2*)(logits + (size_t)n * 128))[lane];

            float m = fmaxf(x.x, x.y);
            #pragma unroll
            for (int off = 32; off > 0; off >>= 1)
                m = fmaxf(m, __shfl_xor(m, off));

            float e0 = __expf(x.x - m);
            float e1 = __expf(x.y - m);
            float s = e0 + e1;
            #pragma unroll
            for (int off = 32; off > 0; off >>= 1)
                s += __shfl_xor(s, off);
            float inv = fast_rcp_nr(s);

            float p0 = e0 * inv, p1 = e1 * inv;
            float omp0 = 1.0f - p0, omp1 = 1.0f - p1;
            float d0 = F_ALPHA * omp0 * omp0 * (-__logf(p0 + F_EPS))
                     - (1.0f - F_ALPHA) * p0 * p0 * (-__logf(omp0 + F_EPS));
            float d1 = F_ALPHA * omp1 * omp1 * (-__logf(p1 + F_EPS))
                     - (1.0f - F_ALPHA) * p1 * p1 * (-__logf(omp1 + F_EPS));

            f2 o; o.x = d0; o.y = d1;
            ((f2*)(delta + lr * 128))[lane] = o;     // 8B stride: conflict-free
        }
    }
    __syncthreads();

    // ---------------- Phase B: 5 target chunks ----------------
    const int lt2 = threadIdx.x * 2;   // this thread's target pair within chunk

    #pragma unroll 1
    for (int ct = 0; ct < 5; ++ct) {
        const int t0 = ct * TCHUNK + lt2;

        const float4 tbA = tgt_bbox[t0];
        const float4 tbB = tgt_bbox[t0 + 1];
        const int idA = tgt_ids[t0];
        const int idB = tgt_ids[t0 + 1];

        // target xyxy + area (hoisted across all 10 rows)
        const float ax0 = fmaf(-0.5f, tbA.z, tbA.x), ay0 = fmaf(-0.5f, tbA.w, tbA.y);
        const float ax1 = fmaf( 0.5f, tbA.z, tbA.x), ay1 = fmaf( 0.5f, tbA.w, tbA.y);
        const float areaA = tbA.z * tbA.w;
        const float bx0 = fmaf(-0.5f, tbB.z, tbB.x), by0 = fmaf(-0.5f, tbB.w, tbB.y);
        const float bx1 = fmaf( 0.5f, tbB.z, tbB.x), by1 = fmaf( 0.5f, tbB.w, tbB.y);
        const float areaB = tbB.z * tbB.w;

        const size_t obase = (size_t)n0 * (size_t)T + (size_t)t0;

        #pragma unroll
        for (int r = 0; r < ROWS; ++r) {
            const float4 pb = pred_boxes[n0 + r];    // block-uniform -> scalar load
            const float px0 = fmaf(-0.5f, pb.z, pb.x), py0 = fmaf(-0.5f, pb.w, pb.y);
            const float px1 = fmaf( 0.5f, pb.z, pb.x), py1 = fmaf( 0.5f, pb.w, pb.y);
            const float parea = pb.z * pb.w;

            const float dA = delta[r * 128 + idA];   // ds_read, imm offset r*512
            const float dB = delta[r * 128 + idB];

            // ---- target A ----
            float cbA = fabsf(pb.x - tbA.x) + fabsf(pb.y - tbA.y)
                      + fabsf(pb.z - tbA.z) + fabsf(pb.w - tbA.w);
            // intersection raw extents (reused for enclosure via a+b identity)
            float iwrA = fminf(px1, ax1) - fmaxf(px0, ax0);
            float ihrA = fminf(py1, ay1) - fmaxf(py0, ay0);
            float interA = fmaxf(iwrA, 0.0f) * fmaxf(ihrA, 0.0f);
            float uniA = parea + areaA - interA;
            // ew = pw + tw - iw_raw  (max+min = sum)
            float ewA = (pb.z + tbA.z) - iwrA;
            float ehA = (pb.w + tbA.w) - ihrA;
            float eareaA = ewA * ehA;
            // giou = inter*rcp(uni) + uni*rcp(earea) - 1
            float termsA = fmaf(interA, __builtin_amdgcn_rcpf(uniA),
                                uniA * __builtin_amdgcn_rcpf(eareaA));
            // C = 5*cb + d + 2 - 2*terms
            float cA = fmaf(W_BBOX, cbA, dA + 2.0f);
            cA = fmaf(-W_GIOU, termsA, cA);

            // ---- target B ----
            float cbB = fabsf(pb.x - tbB.x) + fabsf(pb.y - tbB.y)
                      + fabsf(pb.z - tbB.z) + fabsf(pb.w - tbB.w);
            float iwrB = fminf(px1, bx1) - fmaxf(px0, bx0);
            float ihrB = fminf(py1, by1) - fmaxf(py0, by0);
            float interB = fmaxf(iwrB, 0.0f) * fmaxf(ihrB, 0.0f);
            float uniB = parea + areaB - interB;
            float ewB = (pb.z + tbB.z) - iwrB;
            float ehB = (pb.w + tbB.w) - ihrB;
            float eareaB = ewB * ehB;
            float termsB = fmaf(interB, __builtin_amdgcn_rcpf(uniB),
                                uniB * __builtin_amdgcn_rcpf(eareaB));
            float cB = fmaf(W_BBOX, cbB, dB + 2.0f);
            cB = fmaf(-W_GIOU, termsB, cB);

            f2 o; o.x = cA; o.y = cB;
            // write-once, zero-reuse: bypass L2
            __builtin_nontemporal_store(o, (f2*)(out + obase + (size_t)r * (size_t)T));
        }
    }
}

extern "C" void kernel_launch(void* const* d_in, const int* in_sizes, int n_in,
                              void* d_out, int out_size, void* d_ws, size_t ws_size,
                              hipStream_t stream) {
    const float* pred_logits = (const float*)d_in[0];   // [16,900,128] f32
    const float* pred_boxes  = (const float*)d_in[1];   // [16,900,4]  f32
    const int*   tgt_ids     = (const int*)d_in[2];     // [3200] int32
    const float* tgt_bbox    = (const float*)d_in[3];   // [3200,4] f32
    float* out = (float*)d_out;
    (void)d_ws; (void)ws_size;

    const int N = in_sizes[1] / 4;   // bs*Q = 14400
    const int T = in_sizes[2];       // 3200

    fused_cost_kernel<<<N / ROWS, TPB, 0, stream>>>(
        pred_logits, (const float4*)pred_boxes, (const float4*)tgt_bbox,
        tgt_ids, out, T);
}

// Round 6
// 217.875 us; speedup vs baseline: 1.0356x; 1.0356x over previous
//
#include <hip/hip_runtime.h>
#include <math.h>

// Cost weights / focal params (match reference)
#define W_CLASS 1.0f
#define W_BBOX  5.0f
#define W_GIOU  2.0f
#define F_ALPHA 0.25f
#define F_EPS   1e-8f

typedef float f2 __attribute__((ext_vector_type(2)));

// v_rcp_f32 + one Newton step (bit-identical softmax denominator vs passing runs)
__device__ __forceinline__ float fast_rcp_nr(float x) {
    float r = __builtin_amdgcn_rcpf(x);
    r = fmaf(fmaf(-x, r, 1.0f), r, r);
    return r;
}

// Phase 1: per-row softmax over C=128 logits + focal class-cost table.
// Identical math to the round-1 passing version (absmax 0.0625).
__global__ __launch_bounds__(256)
void class_cost_kernel(const float* __restrict__ logits,
                       float* __restrict__ delta) {
    const int wave = threadIdx.x >> 6;
    const int lane = threadIdx.x & 63;
    const int n = blockIdx.x * 4 + wave;

    f2 x = ((const f2*)(logits + (size_t)n * 128))[lane];

    float m = fmaxf(x.x, x.y);
    #pragma unroll
    for (int off = 32; off > 0; off >>= 1)
        m = fmaxf(m, __shfl_xor(m, off));

    float e0 = __expf(x.x - m);
    float e1 = __expf(x.y - m);
    float s = e0 + e1;
    #pragma unroll
    for (int off = 32; off > 0; off >>= 1)
        s += __shfl_xor(s, off);
    float inv = fast_rcp_nr(s);

    float p0 = e0 * inv, p1 = e1 * inv;
    float omp0 = 1.0f - p0, omp1 = 1.0f - p1;
    float d0 = F_ALPHA * omp0 * omp0 * (-__logf(p0 + F_EPS))
             - (1.0f - F_ALPHA) * p0 * p0 * (-__logf(omp0 + F_EPS));
    float d1 = F_ALPHA * omp1 * omp1 * (-__logf(p1 + F_EPS))
             - (1.0f - F_ALPHA) * p1 * p1 * (-__logf(omp1 + F_EPS));

    f2 o; o.x = d0; o.y = d1;
    ((f2*)(delta + (size_t)n * 128))[lane] = o;
}

// Phase 2: full cost matrix. EXPERIMENT AXIS: store pattern now matches the
// harness fill's proven-fast pattern — regular (through-L2) float4 stores,
// 16 B/lane, 4 consecutive targets per thread. All other math identical to
// the round-5 passing version.
#define RPB 4   // pred rows per block

__global__ __launch_bounds__(256)
void cost_kernel(const float4* __restrict__ pred_boxes,   // [N,4] cxcywh
                 const float4* __restrict__ tgt_bbox,     // [T,4] cxcywh
                 const int* __restrict__ tgt_ids,         // [T]
                 const float* __restrict__ delta,         // [N,128]
                 float* __restrict__ out,                 // [N,T]
                 int T) {
    const int t0 = (blockIdx.x * blockDim.x + threadIdx.x) * 4;
    if (t0 >= T) return;   // trailing waves fully idle -> retire immediately; no barriers

    // 4 consecutive targets per thread (vector loads: 1x int4 + 4x float4)
    const int4 idv = *(const int4*)(tgt_ids + t0);
    const int id[4] = { idv.x, idv.y, idv.z, idv.w };

    float4 tb[4];
    float tx0[4], ty0[4], tx1[4], ty1[4], tarea[4];
    #pragma unroll
    for (int j = 0; j < 4; ++j) {
        tb[j] = tgt_bbox[t0 + j];
        tx0[j] = fmaf(-0.5f, tb[j].z, tb[j].x);
        ty0[j] = fmaf(-0.5f, tb[j].w, tb[j].y);
        tx1[j] = fmaf( 0.5f, tb[j].z, tb[j].x);
        ty1[j] = fmaf( 0.5f, tb[j].w, tb[j].y);
        tarea[j] = tb[j].z * tb[j].w;
    }

    const int n0 = blockIdx.y * RPB;

    #pragma unroll
    for (int r = 0; r < RPB; ++r) {
        const int n = n0 + r;
        const float4 pb = pred_boxes[n];   // block-uniform -> scalar load
        const float px0 = fmaf(-0.5f, pb.z, pb.x), py0 = fmaf(-0.5f, pb.w, pb.y);
        const float px1 = fmaf( 0.5f, pb.z, pb.x), py1 = fmaf( 0.5f, pb.w, pb.y);
        const float parea = pb.z * pb.w;
        const float* drow = delta + n * 128;

        float c[4];
        #pragma unroll
        for (int j = 0; j < 4; ++j) {
            const float d = drow[id[j]];   // 4B gather within 512B row (L1-resident)

            float cb = fabsf(pb.x - tb[j].x) + fabsf(pb.y - tb[j].y)
                     + fabsf(pb.z - tb[j].z) + fabsf(pb.w - tb[j].w);

            // intersection raw extents (reused for enclosure via max+min=sum)
            float iwr = fminf(px1, tx1[j]) - fmaxf(px0, tx0[j]);
            float ihr = fminf(py1, ty1[j]) - fmaxf(py0, ty0[j]);
            float inter = fmaxf(iwr, 0.0f) * fmaxf(ihr, 0.0f);
            float uni = parea + tarea[j] - inter;
            float ew = (pb.z + tb[j].z) - iwr;
            float eh = (pb.w + tb[j].w) - ihr;
            float earea = ew * eh;

            // giou = inter*rcp(uni) + uni*rcp(earea) - 1
            float terms = fmaf(inter, __builtin_amdgcn_rcpf(uni),
                               uni * __builtin_amdgcn_rcpf(earea));
            // C = 5*cb + d + 2 - 2*terms
            float cc = fmaf(W_BBOX, cb, d + 2.0f);
            c[j] = fmaf(-W_GIOU, terms, cc);
        }

        float4 o; o.x = c[0]; o.y = c[1]; o.z = c[2]; o.w = c[3];
        // REGULAR store through L2 (the fill's pattern) — NT removed on purpose
        *(float4*)(out + (size_t)n * T + t0) = o;
    }
}

extern "C" void kernel_launch(void* const* d_in, const int* in_sizes, int n_in,
                              void* d_out, int out_size, void* d_ws, size_t ws_size,
                              hipStream_t stream) {
    const float* pred_logits = (const float*)d_in[0];   // [16,900,128] f32
    const float* pred_boxes  = (const float*)d_in[1];   // [16,900,4]  f32
    const int*   tgt_ids     = (const int*)d_in[2];     // [3200] int32
    const float* tgt_bbox    = (const float*)d_in[3];   // [3200,4] f32
    float* out = (float*)d_out;
    float* delta = (float*)d_ws;                        // [14400,128] f32 = 7.4 MB

    const int N = in_sizes[1] / 4;   // bs*Q = 14400
    const int T = in_sizes[2];       // 3200

    // Phase 1: class-cost table (one wave per row, 4 rows/block)
    class_cost_kernel<<<N / 4, 256, 0, stream>>>(pred_logits, delta);

    // Phase 2: full cost matrix, 4 targets/thread, float4 stores
    dim3 grid((T / 4 + 255) / 256, N / RPB);   // (4, 3600)
    cost_kernel<<<grid, 256, 0, stream>>>(
        (const float4*)pred_boxes, (const float4*)tgt_bbox, tgt_ids, delta, out, T);
}

// Round 7
// 207.855 us; speedup vs baseline: 1.0855x; 1.0482x over previous
//
#include <hip/hip_runtime.h>
#include <math.h>

// Cost weights / focal params (match reference)
#define W_CLASS 1.0f
#define W_BBOX  5.0f
#define W_GIOU  2.0f
#define F_ALPHA 0.25f
#define F_EPS   1e-8f

typedef float f2 __attribute__((ext_vector_type(2)));

// v_rcp_f32 + one Newton step (bit-identical softmax denominator vs passing runs)
__device__ __forceinline__ float fast_rcp_nr(float x) {
    float r = __builtin_amdgcn_rcpf(x);
    r = fmaf(fmaf(-x, r, 1.0f), r, r);
    return r;
}

// Phase 1: per-row softmax over C=128 logits + focal class-cost table.
// Identical math to the round-1 passing version.
__global__ __launch_bounds__(256)
void class_cost_kernel(const float* __restrict__ logits,
                       float* __restrict__ delta) {
    const int wave = threadIdx.x >> 6;
    const int lane = threadIdx.x & 63;
    const int n = blockIdx.x * 4 + wave;

    f2 x = ((const f2*)(logits + (size_t)n * 128))[lane];

    float m = fmaxf(x.x, x.y);
    #pragma unroll
    for (int off = 32; off > 0; off >>= 1)
        m = fmaxf(m, __shfl_xor(m, off));

    float e0 = __expf(x.x - m);
    float e1 = __expf(x.y - m);
    float s = e0 + e1;
    #pragma unroll
    for (int off = 32; off > 0; off >>= 1)
        s += __shfl_xor(s, off);
    float inv = fast_rcp_nr(s);

    float p0 = e0 * inv, p1 = e1 * inv;
    float omp0 = 1.0f - p0, omp1 = 1.0f - p1;
    float d0 = F_ALPHA * omp0 * omp0 * (-__logf(p0 + F_EPS))
             - (1.0f - F_ALPHA) * p0 * p0 * (-__logf(omp0 + F_EPS));
    float d1 = F_ALPHA * omp1 * omp1 * (-__logf(p1 + F_EPS))
             - (1.0f - F_ALPHA) * p1 * p1 * (-__logf(omp1 + F_EPS));

    f2 o; o.x = d0; o.y = d1;
    ((f2*)(delta + (size_t)n * 128))[lane] = o;
}

// Phase 2: identical to round 6 EXCEPT the single experimental axis:
// the per-element delta gathers (divergent global_load_dword -> TA-coalescing
// serialization) are replaced by ds_read from a cooperatively staged LDS copy
// of the block's 4 delta rows (2 KB, one coalesced 8B load per thread).
#define RPB 4   // pred rows per block == waves per block (cooperative stage)

__global__ __launch_bounds__(256)
void cost_kernel(const float4* __restrict__ pred_boxes,   // [N,4] cxcywh
                 const float4* __restrict__ tgt_bbox,     // [T,4] cxcywh
                 const int* __restrict__ tgt_ids,         // [T]
                 const float* __restrict__ delta,         // [N,128]
                 float* __restrict__ out,                 // [N,T]
                 int T) {
    __shared__ float dl[RPB * 128];   // 2 KB

    const int n0 = blockIdx.y * RPB;

    // Cooperative delta stage: wave w loads row w (64 lanes x 8B = 512B, coalesced)
    {
        const int w = threadIdx.x >> 6;
        const int l = threadIdx.x & 63;
        f2 v = ((const f2*)(delta + (size_t)(n0 + w) * 128))[l];
        ((f2*)(dl + w * 128))[l] = v;    // 8B stride: conflict-free
    }
    __syncthreads();

    const int t0 = (blockIdx.x * blockDim.x + threadIdx.x) * 4;
    if (t0 < T) {
        // 4 consecutive targets per thread (vector loads: 1x int4 + 4x float4)
        const int4 idv = *(const int4*)(tgt_ids + t0);
        const int id[4] = { idv.x, idv.y, idv.z, idv.w };

        float4 tb[4];
        float tx0[4], ty0[4], tx1[4], ty1[4], tarea[4];
        #pragma unroll
        for (int j = 0; j < 4; ++j) {
            tb[j] = tgt_bbox[t0 + j];
            tx0[j] = fmaf(-0.5f, tb[j].z, tb[j].x);
            ty0[j] = fmaf(-0.5f, tb[j].w, tb[j].y);
            tx1[j] = fmaf( 0.5f, tb[j].z, tb[j].x);
            ty1[j] = fmaf( 0.5f, tb[j].w, tb[j].y);
            tarea[j] = tb[j].z * tb[j].w;
        }

        #pragma unroll
        for (int r = 0; r < RPB; ++r) {
            const int n = n0 + r;
            const float4 pb = pred_boxes[n];   // block-uniform -> scalar load
            const float px0 = fmaf(-0.5f, pb.z, pb.x), py0 = fmaf(-0.5f, pb.w, pb.y);
            const float px1 = fmaf( 0.5f, pb.z, pb.x), py1 = fmaf( 0.5f, pb.w, pb.y);
            const float parea = pb.z * pb.w;

            float c[4];
            #pragma unroll
            for (int j = 0; j < 4; ++j) {
                const float d = dl[r * 128 + id[j]];   // ds_read, ~2-way alias: free

                float cb = fabsf(pb.x - tb[j].x) + fabsf(pb.y - tb[j].y)
                         + fabsf(pb.z - tb[j].z) + fabsf(pb.w - tb[j].w);

                // intersection raw extents (reused for enclosure via max+min=sum)
                float iwr = fminf(px1, tx1[j]) - fmaxf(px0, tx0[j]);
                float ihr = fminf(py1, ty1[j]) - fmaxf(py0, ty0[j]);
                float inter = fmaxf(iwr, 0.0f) * fmaxf(ihr, 0.0f);
                float uni = parea + tarea[j] - inter;
                float ew = (pb.z + tb[j].z) - iwr;
                float eh = (pb.w + tb[j].w) - ihr;
                float earea = ew * eh;

                // giou = inter*rcp(uni) + uni*rcp(earea) - 1
                float terms = fmaf(inter, __builtin_amdgcn_rcpf(uni),
                                   uni * __builtin_amdgcn_rcpf(earea));
                // C = 5*cb + d + 2 - 2*terms
                float cc = fmaf(W_BBOX, cb, d + 2.0f);
                c[j] = fmaf(-W_GIOU, terms, cc);
            }

            float4 o; o.x = c[0]; o.y = c[1]; o.z = c[2]; o.w = c[3];
            *(float4*)(out + (size_t)n * T + t0) = o;   // regular store (round-6 mode)
        }
    }
}

extern "C" void kernel_launch(void* const* d_in, const int* in_sizes, int n_in,
                              void* d_out, int out_size, void* d_ws, size_t ws_size,
                              hipStream_t stream) {
    const float* pred_logits = (const float*)d_in[0];   // [16,900,128] f32
    const float* pred_boxes  = (const float*)d_in[1];   // [16,900,4]  f32
    const int*   tgt_ids     = (const int*)d_in[2];     // [3200] int32
    const float* tgt_bbox    = (const float*)d_in[3];   // [3200,4] f32
    float* out = (float*)d_out;
    float* delta = (float*)d_ws;                        // [14400,128] f32 = 7.4 MB

    const int N = in_sizes[1] / 4;   // bs*Q = 14400
    const int T = in_sizes[2];       // 3200

    // Phase 1: class-cost table (one wave per row, 4 rows/block)
    class_cost_kernel<<<N / 4, 256, 0, stream>>>(pred_logits, delta);

    // Phase 2: full cost matrix, 4 targets/thread, LDS-staged delta gathers
    dim3 grid((T / 4 + 255) / 256, N / RPB);   // (4, 3600)
    cost_kernel<<<grid, 256, 0, stream>>>(
        (const float4*)pred_boxes, (const float4*)tgt_bbox, tgt_ids, delta, out, T);
}